// Round 10
// baseline (175.891 us; speedup 1.0000x reference)
//
#include <hip/hip_runtime.h>
#include <math.h>

typedef float v4f __attribute__((ext_vector_type(4)));

#define CUT  4.0f
#define EPS  1e-11f
#define BOHR 0.5291772105638411f
#define PI_F 3.14159265358979323846f

#define LDS_FLOATS 18432   // 72 KB: src(3N)+tgt(3M) for N=4096,M=2048
#define T 8                // tiles per phase-chunk

__device__ __forceinline__ float bperm(unsigned int lane, float v) {
    return __int_as_float(
        __builtin_amdgcn_ds_bpermute((int)(lane << 2), __float_as_int(v)));
}

// Phased + low-wave-count variant: 2048 waves total (vs 8192), each wave owns
// a contiguous tile range and writes ONE output array per phase, so the
// number of concurrent DRAM write streams (~3K) stays below the HBM bank
// count. Inputs staged in LDS (R9), so no loads in the steady-state loop.
__global__ __launch_bounds__(256) void deepdft_phased_kernel(
    const float* __restrict__ src,
    const float* __restrict__ tgt,
    float* __restrict__ out,
    unsigned int N, unsigned int M)
{
    __shared__ __align__(16) float lds[LDS_FLOATS];
    float* lsrc = lds;            // 3N floats
    float* ltgt = lds + 3u * N;   // 3M floats

    const unsigned int total = N * M;
    const unsigned int tid   = threadIdx.x;

    // ---- one-time stage: global -> LDS ----
    {
        const unsigned int ns = 3u * N;
        const unsigned int nt = 3u * M;
        if ((ns & 3u) == 0u && (nt & 3u) == 0u) {
            const unsigned int ns4 = ns >> 2, nt4 = nt >> 2;
            for (unsigned int i = tid; i < ns4; i += blockDim.x)
                ((v4f*)lsrc)[i] = ((const v4f*)src)[i];
            for (unsigned int i = tid; i < nt4; i += blockDim.x)
                ((v4f*)ltgt)[i] = ((const v4f*)tgt)[i];
        } else {
            for (unsigned int i = tid; i < ns; i += blockDim.x) lsrc[i] = src[i];
            for (unsigned int i = tid; i < nt; i += blockDim.x) ltgt[i] = tgt[i];
        }
    }
    __syncthreads();

    float* __restrict__ dist_o = out;
    float* __restrict__ dir_o  = out + (size_t)total;          // [total][3]
    float* __restrict__ mask_o = out + (size_t)4 * total;      // [total]
    float* __restrict__ exp_o  = out + (size_t)5 * total;      // [total][20]

    const unsigned int lane   = tid & 63u;
    const unsigned int waves  = (gridDim.x * blockDim.x) >> 6;
    const unsigned int wtiles = (total + 63u) >> 6;
    const unsigned int wid    = (blockIdx.x * blockDim.x + tid) >> 6;

    // contiguous per-wave tile range
    const unsigned int chunk = (wtiles + waves - 1u) / waves;
    const unsigned int tbeg  = wid * chunk;
    const unsigned int tend  = (tbeg + chunk < wtiles) ? (tbeg + chunk) : wtiles;

    for (unsigned int c = tbeg; c < tend; c += T) {
        const unsigned int nt = (tend - c < T) ? (tend - c) : T;
        float rux[T], ruy[T], ruz[T], rx[T], rinv[T];

        // ---- phase 1: geometry for T tiles; write dist + mask streams ----
        #pragma unroll
        for (unsigned int t = 0; t < T; ++t) {
            if (t < nt) {
                const unsigned int base = (c + t) << 6;
                const unsigned int idx  = base + lane;
                const unsigned int cidx = (idx < total) ? idx : (total - 1u);
                unsigned int n = cidx / M;
                unsigned int m = cidx - n * M;

                float sx = lsrc[3u*n + 0], sy = lsrc[3u*n + 1], sz = lsrc[3u*n + 2];
                float tx = ltgt[3u*m + 0], ty = ltgt[3u*m + 1], tz = ltgt[3u*m + 2];

                float dx = tx - sx, dy = ty - sy, dz = tz - sz;
                float dist = sqrtf(fmaf(dx, dx, fmaf(dy, dy, dz * dz)));
                float inv  = 1.0f / (dist + EPS);

                if (idx < total) {
                    dist_o[idx] = dist;
                    mask_o[idx] = (dist < CUT) ? 1.0f : 0.0f;
                }
                rux[t] = dx * inv;
                ruy[t] = dy * inv;
                ruz[t] = dz * inv;
                float d = fmaf(dist, BOHR, EPS);
                rinv[t] = 1.0f / d;
                rx[t]   = (PI_F / CUT) * d;
            }
        }

        // ---- phase 2: direction stream only ----
        #pragma unroll
        for (unsigned int t = 0; t < T; ++t) {
            if (t < nt) {
                const unsigned int base = (c + t) << 6;
                float* gdir = dir_o + (size_t)3 * base;
                #pragma unroll
                for (int k = 0; k < 3; ++k) {
                    unsigned int e = lane + 64u * (unsigned)k;   // e < 192
                    unsigned int p = (e * 10923u) >> 15;         // e / 3
                    unsigned int cc = e - 3u * p;                // e % 3
                    float vx = bperm(p, rux[t]);
                    float vy = bperm(p, ruy[t]);
                    float vz = bperm(p, ruz[t]);
                    float val = (cc == 0u) ? vx : ((cc == 1u) ? vy : vz);
                    if (base + p < total) gdir[e] = val;
                }
            }
        }

        // ---- phase 3: expansion stream only ----
        #pragma unroll
        for (unsigned int t = 0; t < T; ++t) {
            if (t < nt) {
                const unsigned int base = (c + t) << 6;
                v4f* gexp = reinterpret_cast<v4f*>(exp_o) + (size_t)5 * base;
                #pragma unroll
                for (int k = 0; k < 5; ++k) {
                    unsigned int j = lane + 64u * (unsigned)k;   // < 320
                    unsigned int p = (j * 6554u) >> 15;          // j / 5
                    unsigned int g = j - 5u * p;                 // j % 5
                    float xv = bperm(p, rx[t]);
                    float iv = bperm(p, rinv[t]);
                    float n0 = (float)(4u * g + 1u);
                    v4f v;
                    v.x = __sinf( n0         * xv) * iv;
                    v.y = __sinf((n0 + 1.0f) * xv) * iv;
                    v.z = __sinf((n0 + 2.0f) * xv) * iv;
                    v.w = __sinf((n0 + 3.0f) * xv) * iv;
                    if (base + p < total) gexp[j] = v;
                }
            }
        }
    }
}

// Fallback (round-3 body, global loads) for shapes that don't fit the stage.
__global__ __launch_bounds__(256) void deepdft_global_kernel(
    const float* __restrict__ src,
    const float* __restrict__ tgt,
    float* __restrict__ out,
    unsigned int N, unsigned int M)
{
    const unsigned int total = N * M;
    float* __restrict__ dist_o = out;
    float* __restrict__ dir_o  = out + (size_t)total;
    float* __restrict__ mask_o = out + (size_t)4 * total;
    float* __restrict__ exp_o  = out + (size_t)5 * total;

    const unsigned int lane   = threadIdx.x & 63u;
    const unsigned int waves  = (gridDim.x * blockDim.x) >> 6;
    const unsigned int wtiles = (total + 63u) >> 6;

    for (unsigned int w = (blockIdx.x * blockDim.x + threadIdx.x) >> 6;
         w < wtiles; w += waves) {
        const unsigned int base = w << 6;
        const unsigned int idx  = base + lane;
        const unsigned int cidx = (idx < total) ? idx : (total - 1u);
        unsigned int n = cidx / M;
        unsigned int m = cidx - n * M;

        float sx = src[3u*n + 0], sy = src[3u*n + 1], sz = src[3u*n + 2];
        float tx = tgt[3u*m + 0], ty = tgt[3u*m + 1], tz = tgt[3u*m + 2];
        float dx = tx - sx, dy = ty - sy, dz = tz - sz;
        float dist = sqrtf(fmaf(dx, dx, fmaf(dy, dy, dz * dz)));
        float inv  = 1.0f / (dist + EPS);

        if (idx < total) {
            dist_o[idx] = dist;
            mask_o[idx] = (dist < CUT) ? 1.0f : 0.0f;
        }
        float ux = dx * inv, uy = dy * inv, uz = dz * inv;
        float d    = fmaf(dist, BOHR, EPS);
        float invd = 1.0f / d;
        float x    = (PI_F / CUT) * d;

        {
            float* gdir = dir_o + (size_t)3 * base;
            #pragma unroll
            for (int k = 0; k < 3; ++k) {
                unsigned int e = lane + 64u * (unsigned)k;
                unsigned int p = (e * 10923u) >> 15;
                unsigned int cc = e - 3u * p;
                float vx = bperm(p, ux);
                float vy = bperm(p, uy);
                float vz = bperm(p, uz);
                float val = (cc == 0u) ? vx : ((cc == 1u) ? vy : vz);
                if (base + p < total) gdir[e] = val;
            }
        }
        {
            v4f* gexp = reinterpret_cast<v4f*>(exp_o) + (size_t)5 * base;
            #pragma unroll
            for (int k = 0; k < 5; ++k) {
                unsigned int j = lane + 64u * (unsigned)k;
                unsigned int p = (j * 6554u) >> 15;
                unsigned int g = j - 5u * p;
                float xv = bperm(p, x);
                float iv = bperm(p, invd);
                float n0 = (float)(4u * g + 1u);
                v4f v;
                v.x = __sinf( n0         * xv) * iv;
                v.y = __sinf((n0 + 1.0f) * xv) * iv;
                v.z = __sinf((n0 + 2.0f) * xv) * iv;
                v.w = __sinf((n0 + 3.0f) * xv) * iv;
                if (base + p < total) gexp[j] = v;
            }
        }
    }
}

extern "C" void kernel_launch(void* const* d_in, const int* in_sizes, int n_in,
                              void* d_out, int out_size, void* d_ws, size_t ws_size,
                              hipStream_t stream) {
    const float* src = (const float*)d_in[0];   // [1, N, 3] float32
    const float* tgt = (const float*)d_in[1];   // [1, M, 3] float32
    float* out = (float*)d_out;

    unsigned int N = (unsigned int)(in_sizes[0] / 3);
    unsigned int M = (unsigned int)(in_sizes[1] / 3);
    unsigned int total = N * M;
    unsigned int wtiles = (total + 63u) >> 6;

    if (3u * (N + M) <= (unsigned)LDS_FLOATS) {
        // LOW wave count: 512 blocks = 2048 waves -> ~3K concurrent write
        // streams (phased), below HBM bank count. Compute has ~6x slack.
        unsigned int blocks = (wtiles + 3u) / 4u;
        if (blocks > 512u) blocks = 512u;
        deepdft_phased_kernel<<<blocks, 256, 0, stream>>>(src, tgt, out, N, M);
    } else {
        unsigned int blocks = (wtiles + 3u) / 4u;
        if (blocks > 2048u) blocks = 2048u;
        deepdft_global_kernel<<<blocks, 256, 0, stream>>>(src, tgt, out, N, M);
    }
}

// Round 11
// 166.335 us; speedup vs baseline: 1.0574x; 1.0574x over previous
//
#include <hip/hip_runtime.h>
#include <math.h>

typedef float v4f __attribute__((ext_vector_type(4)));

#define CUT  4.0f
#define EPS  1e-11f
#define BOHR 0.5291772105638411f
#define PI_F 3.14159265358979323846f

__device__ __forceinline__ float bperm(unsigned int lane, float v) {
    return __int_as_float(
        __builtin_amdgcn_ds_bpermute((int)(lane << 2), __float_as_int(v)));
}

// ---------------- Kernel A: expansion only (671 MB, pure dwordx4) ----------
// While this kernel runs, DRAM sees exactly ONE output array being written,
// wave-contiguous 1 KiB per store — maximally fill-like.
__global__ __launch_bounds__(256) void deepdft_exp_kernel(
    const float* __restrict__ src,
    const float* __restrict__ tgt,
    float* __restrict__ out,
    unsigned int N, unsigned int M)
{
    const unsigned int total = N * M;
    float* __restrict__ exp_o = out + (size_t)5 * total;   // [total][20]

    const unsigned int lane   = threadIdx.x & 63u;
    const unsigned int waves  = (gridDim.x * blockDim.x) >> 6;
    const unsigned int wtiles = (total + 63u) >> 6;

    for (unsigned int w = (blockIdx.x * blockDim.x + threadIdx.x) >> 6;
         w < wtiles; w += waves) {
        const unsigned int base = w << 6;
        const unsigned int idx  = base + lane;
        const unsigned int cidx = (idx < total) ? idx : (total - 1u);

        unsigned int n = cidx / M;
        unsigned int m = cidx - n * M;

        float sx = src[3u*n + 0], sy = src[3u*n + 1], sz = src[3u*n + 2];
        float tx = tgt[3u*m + 0], ty = tgt[3u*m + 1], tz = tgt[3u*m + 2];

        float dx = tx - sx, dy = ty - sy, dz = tz - sz;
        float dist = sqrtf(fmaf(dx, dx, fmaf(dy, dy, dz * dz)));
        float d    = fmaf(dist, BOHR, EPS);
        float invd = 1.0f / d;
        float x    = (PI_F / CUT) * d;                   // x = pi*d/CUT

        v4f* gexp = reinterpret_cast<v4f*>(exp_o) + (size_t)5 * base;
        #pragma unroll
        for (int k = 0; k < 5; ++k) {
            unsigned int j = lane + 64u * (unsigned)k;    // v4 idx < 320
            unsigned int p = (j * 6554u) >> 15;           // j / 5
            unsigned int g = j - 5u * p;                  // j % 5
            float xv = bperm(p, x);
            float iv = bperm(p, invd);
            float n0 = (float)(4u * g + 1u);              // first n of group
            v4f v;
            v.x = __sinf( n0         * xv) * iv;
            v.y = __sinf((n0 + 1.0f) * xv) * iv;
            v.z = __sinf((n0 + 2.0f) * xv) * iv;
            v.w = __sinf((n0 + 3.0f) * xv) * iv;
            if (base + p < total) gexp[j] = v;            // coalesced 1 KiB/wave
        }
    }
}

// ---------------- Kernel B: dist + mask + direction (168 MB) ---------------
__global__ __launch_bounds__(256) void deepdft_geo_kernel(
    const float* __restrict__ src,
    const float* __restrict__ tgt,
    float* __restrict__ out,
    unsigned int N, unsigned int M)
{
    const unsigned int total = N * M;
    float* __restrict__ dist_o = out;
    float* __restrict__ dir_o  = out + (size_t)total;          // [total][3]
    float* __restrict__ mask_o = out + (size_t)4 * total;      // [total]

    const unsigned int lane   = threadIdx.x & 63u;
    const unsigned int waves  = (gridDim.x * blockDim.x) >> 6;
    const unsigned int wtiles = (total + 63u) >> 6;

    for (unsigned int w = (blockIdx.x * blockDim.x + threadIdx.x) >> 6;
         w < wtiles; w += waves) {
        const unsigned int base = w << 6;
        const unsigned int idx  = base + lane;
        const unsigned int cidx = (idx < total) ? idx : (total - 1u);

        unsigned int n = cidx / M;
        unsigned int m = cidx - n * M;

        float sx = src[3u*n + 0], sy = src[3u*n + 1], sz = src[3u*n + 2];
        float tx = tgt[3u*m + 0], ty = tgt[3u*m + 1], tz = tgt[3u*m + 2];

        float dx = tx - sx, dy = ty - sy, dz = tz - sz;
        float dist = sqrtf(fmaf(dx, dx, fmaf(dy, dy, dz * dz)));
        float inv  = 1.0f / (dist + EPS);

        if (idx < total) {
            dist_o[idx] = dist;                          // coalesced dword
            mask_o[idx] = (dist < CUT) ? 1.0f : 0.0f;    // coalesced dword
        }

        float ux = dx * inv, uy = dy * inv, uz = dz * inv;

        float* gdir = dir_o + (size_t)3 * base;
        #pragma unroll
        for (int k = 0; k < 3; ++k) {
            unsigned int e = lane + 64u * (unsigned)k;    // e < 192
            unsigned int p = (e * 10923u) >> 15;          // e / 3
            unsigned int c = e - 3u * p;                  // e % 3
            float vx = bperm(p, ux);
            float vy = bperm(p, uy);
            float vz = bperm(p, uz);
            float val = (c == 0u) ? vx : ((c == 1u) ? vy : vz);
            if (base + p < total) gdir[e] = val;          // coalesced dword
        }
    }
}

extern "C" void kernel_launch(void* const* d_in, const int* in_sizes, int n_in,
                              void* d_out, int out_size, void* d_ws, size_t ws_size,
                              hipStream_t stream) {
    const float* src = (const float*)d_in[0];   // [1, N, 3] float32
    const float* tgt = (const float*)d_in[1];   // [1, M, 3] float32
    float* out = (float*)d_out;

    unsigned int N = (unsigned int)(in_sizes[0] / 3);
    unsigned int M = (unsigned int)(in_sizes[1] / 3);
    unsigned int total = N * M;

    const unsigned int block = 256;
    unsigned int wtiles = (total + 63u) >> 6;
    unsigned int blocks = (wtiles + (block / 64) - 1) / (block / 64);
    if (blocks > 2048u) blocks = 2048u;

    // Sequential kernels: DRAM sees one output array at a time (fill-like).
    deepdft_exp_kernel<<<blocks, block, 0, stream>>>(src, tgt, out, N, M);
    deepdft_geo_kernel<<<blocks, block, 0, stream>>>(src, tgt, out, N, M);
}